// Round 2
// baseline (1092.891 us; speedup 1.0000x reference)
//
#include <hip/hip_runtime.h>

typedef __attribute__((ext_vector_type(8))) short bf16x8;
typedef __attribute__((ext_vector_type(4))) float f32x4;

#define DD 512
#define BM 16
#define WW 6
#define EVR 96
#define EVS 520   // evo LDS row stride (bf16 elems), 16B-aligned rows
#define QS  520   // Q/pooled LDS stride
#define SCS 136   // per-wave scratch chunk stride
#define NH 8

__device__ __forceinline__ unsigned short f2bf(float f) {
  unsigned u = __float_as_uint(f);
  u += 0x7fffu + ((u >> 16) & 1u);   // RNE
  return (unsigned short)(u >> 16);
}
__device__ __forceinline__ float bf2f(unsigned short s) { return __uint_as_float(((unsigned)s) << 16); }
__device__ __forceinline__ float bflo(unsigned v) { return __uint_as_float(v << 16); }
__device__ __forceinline__ float bfhi(unsigned v) { return __uint_as_float(v & 0xffff0000u); }
// XOR swizzle on 8-elem blocks; rows differing by 8 or 24 get distinct masks
__device__ __forceinline__ int evsw(int row, int col) {
  return col ^ (((row ^ (row >> 3)) & 7) << 3);
}

// ---------- prep: transpose float[R][C] -> bf16[C][R] ----------
__global__ void k_tr_bf16(const float* __restrict__ src, unsigned short* __restrict__ dst,
                          int R, int C) {
  __shared__ float tile[64][65];
  int tpc = C >> 6;
  int tr = (blockIdx.x / tpc) << 6;
  int tc = (blockIdx.x % tpc) << 6;
  int t = threadIdx.x;
  #pragma unroll
  for (int i = 0; i < 16; ++i) {
    int idx = i * 256 + t; int r = idx >> 6, c = idx & 63;
    tile[r][c] = src[(size_t)(tr + r) * C + tc + c];
  }
  __syncthreads();
  #pragma unroll
  for (int i = 0; i < 16; ++i) {
    int idx = i * 256 + t; int c = idx >> 6, r = idx & 63;
    dst[(size_t)(tc + c) * R + tr + r] = f2bf(tile[r][c]);
  }
}

// ---------- prep: plain convert float -> bf16 (float4 granularity) ----------
__global__ void k_cvt4(const float* __restrict__ src, unsigned short* __restrict__ dst, int n4) {
  int i = blockIdx.x * blockDim.x + threadIdx.x;
  if (i < n4) {
    float4 v = ((const float4*)src)[i];
    ushort4 o; o.x = f2bf(v.x); o.y = f2bf(v.y); o.z = f2bf(v.z); o.w = f2bf(v.w);
    ((ushort4*)dst)[i] = o;
  }
}

// ---------- main fused kernel: 16 entities / block, 8 waves = 8 heads ----------
__global__ __launch_bounds__(512) void trust_main(
    const float* __restrict__ h_i, const float* __restrict__ evo,
    const float* __restrict__ var_i, const float* __restrict__ var_j,
    const float* __restrict__ bq, const float* __restrict__ bk, const float* __restrict__ bv,
    const float* __restrict__ ld, const float* __restrict__ b1,
    const float* __restrict__ W2, const float* __restrict__ b2,
    const unsigned short* __restrict__ wqT, const unsigned short* __restrict__ wkB,
    const unsigned short* __restrict__ wvT, const unsigned short* __restrict__ w1T,
    float* __restrict__ out) {
  __shared__ unsigned short evo_s[EVR * EVS];   // 99840 B, bf16 evo tile (swizzled)
  __shared__ unsigned short q_s[BM * QS];       // 16640 B, Q then pooled (bf16)
  __shared__ unsigned short scr_s[8 * BM * SCS];// 34816 B, per-wave chunk scratch (aliases h tile)
  __shared__ float score_s[NH * BM * WW];       // 3072 B
  __shared__ float logit_s[BM * NH];            // 512 B
  __shared__ float conf_s[BM];                  // 64 B

  const int t = threadIdx.x;
  const int wv = t >> 6;       // wave == head
  const int l = t & 63;
  const int l16 = l & 15;
  const int lq = l >> 4;
  const int blk = blockIdx.x;
  const int e0 = blk * BM;

  // ---- P0: stage evo & h to LDS as bf16; fused conf reduction ----
  {
    const float4* ev4 = (const float4*)evo + (size_t)e0 * (WW * DD / 4);
    #pragma unroll
    for (int i = 0; i < 24; ++i) {
      int idx = i * 512 + t;
      int row = idx >> 7, c4 = idx & 127;
      float4 v = ev4[row * 128 + c4];
      ushort4 o; o.x = f2bf(v.x); o.y = f2bf(v.y); o.z = f2bf(v.z); o.w = f2bf(v.w);
      *(ushort4*)&evo_s[row * EVS + evsw(row, c4 * 4)] = o;
    }
    const float4* h4 = (const float4*)h_i + (size_t)e0 * (DD / 4);
    #pragma unroll
    for (int i = 0; i < 4; ++i) {
      int idx = i * 512 + t;
      int row = idx >> 7, c4 = idx & 127;
      float4 v = h4[row * 128 + c4];
      ushort4 o; o.x = f2bf(v.x); o.y = f2bf(v.y); o.z = f2bf(v.z); o.w = f2bf(v.w);
      *(ushort4*)&scr_s[row * QS + c4 * 4] = o;   // h tile aliases scratch
    }
    int ce = t >> 5, cs = t & 31;
    const float4* vi4 = (const float4*)var_i + (size_t)(e0 + ce) * (DD / 4);
    const float4* vj4 = (const float4*)var_j + (size_t)(e0 + ce) * (DD / 4);
    float si = 0.f, sj = 0.f;
    #pragma unroll
    for (int i = 0; i < 4; ++i) {
      float4 a = vi4[i * 32 + cs]; si += a.x + a.y + a.z + a.w;
      float4 b = vj4[i * 32 + cs]; sj += b.x + b.y + b.z + b.w;
    }
    #pragma unroll
    for (int m = 1; m <= 16; m <<= 1) { si += __shfl_xor(si, m); sj += __shfl_xor(sj, m); }
    if (cs == 0) {
      float ci = 1.f / (1.f + fmaxf(sqrtf(si * (1.f / DD)), 1e-6f));
      float cj = 1.f / (1.f + fmaxf(sqrtf(sj * (1.f / DD)), 1e-6f));
      conf_s[ce] = fmaxf(0.5f * (logf(ci) + logf(cj)), -5.0f);
    }
  }
  __syncthreads();

  // ---- P1: Q = h @ Wq + bq (wave w -> head-w cols), -> q_s bf16 ----
  {
    f32x4 qacc[4] = {};
    #pragma unroll
    for (int kst = 0; kst < 16; ++kst) {
      bf16x8 a = *(const bf16x8*)&scr_s[l16 * QS + kst * 32 + lq * 8];
      #pragma unroll
      for (int ct = 0; ct < 4; ++ct) {
        bf16x8 b = *(const bf16x8*)&wqT[(wv * 64 + ct * 16 + l16) * DD + kst * 32 + lq * 8];
        qacc[ct] = __builtin_amdgcn_mfma_f32_16x16x32_bf16(a, b, qacc[ct], 0, 0, 0);
      }
    }
    #pragma unroll
    for (int ct = 0; ct < 4; ++ct) {
      int col = wv * 64 + ct * 16 + l16;
      float bqv = bq[col];
      #pragma unroll
      for (int r = 0; r < 4; ++r)
        q_s[(lq * 4 + r) * QS + col] = f2bf(qacc[ct][r] + bqv);
    }
  }
  __syncthreads();   // protects h tile (in scr_s) before scratch reuse

  // ---- P2: qb[e] = Q_h[e] . bk_h  (per wave/head) ----
  float qb;
  {
    int e2 = l >> 2, s4 = l & 3;
    float s = 0.f;
    #pragma unroll
    for (int i = 0; i < 16; ++i) {
      int col = wv * 64 + s4 * 16 + i;
      s += bf2f(q_s[e2 * QS + col]) * bk[col];
    }
    s += __shfl_xor(s, 1); s += __shfl_xor(s, 2);
    qb = s;   // lane holds qb for entity l>>2
  }

  // ---- P3: Qk = Q_h (16x64) @ Wk_h^T (64x512), f32 accum in regs ----
  f32x4 qk[32] = {};
  #pragma unroll
  for (int kst = 0; kst < 2; ++kst) {
    bf16x8 a = *(const bf16x8*)&q_s[l16 * QS + wv * 64 + kst * 32 + lq * 8];
    #pragma unroll
    for (int ct = 0; ct < 32; ++ct) {
      bf16x8 b = *(const bf16x8*)&wkB[(ct * 16 + l16) * DD + wv * 64 + kst * 32 + lq * 8];
      qk[ct] = __builtin_amdgcn_mfma_f32_16x16x32_bf16(a, b, qk[ct], 0, 0, 0);
    }
  }

  // ---- P4: S = Qk @ evo^T via MFMA (chunked through per-wave scratch), softmax ----
  float attn[4][6];
  {
    f32x4 sacc[6] = {};
    unsigned short* my = scr_s + wv * (BM * SCS);
    #pragma unroll
    for (int c = 0; c < 4; ++c) {
      // stage ALL 8 column-tiles (128 cols) of this Qk chunk into scratch
      #pragma unroll
      for (int c4i = 0; c4i < 8; ++c4i) {
        #pragma unroll
        for (int r = 0; r < 4; ++r)
          my[(lq * 4 + r) * SCS + c4i * 16 + l16] = f2bf(qk[c * 8 + c4i][r]);
      }
      __syncthreads();
      #pragma unroll
      for (int kst = 0; kst < 4; ++kst) {
        bf16x8 a = *(const bf16x8*)&my[l16 * SCS + kst * 32 + lq * 8];
        #pragma unroll
        for (int n6 = 0; n6 < 6; ++n6) {
          int row = n6 * 16 + l16;
          bf16x8 b = *(const bf16x8*)&evo_s[row * EVS + evsw(row, c * 128 + kst * 32 + lq * 8)];
          sacc[n6] = __builtin_amdgcn_mfma_f32_16x16x32_bf16(a, b, sacc[n6], 0, 0, 0);
        }
      }
      __syncthreads();
    }
    // extract useful entries S[e][6e+w]
    #pragma unroll
    for (int n6 = 0; n6 < 6; ++n6) {
      #pragma unroll
      for (int r = 0; r < 4; ++r) {
        int e = lq * 4 + r;
        int wdx = n6 * 16 + l16 - 6 * e;
        if (wdx >= 0 && wdx < WW)
          score_s[(wv * BM + e) * WW + wdx] = sacc[n6][r];
      }
    }
    __syncthreads();
    // softmax (decay bias + qb, scale 1/8)
    float rd = expf(ld[0]);
    float dwv[6]; float dsum = 0.f;
    #pragma unroll
    for (int w6 = 0; w6 < WW; ++w6) { dwv[w6] = expf(rd * (float)w6); dsum += dwv[w6]; }
    float dinv = 1.f / dsum;
    #pragma unroll
    for (int r = 0; r < 4; ++r) {
      int e = lq * 4 + r;
      float qbv = __shfl(qb, (l & 48) + 4 * r);
      float sc[6]; float mx = -1e30f;
      #pragma unroll
      for (int w6 = 0; w6 < WW; ++w6) {
        sc[w6] = 0.125f * (score_s[(wv * BM + e) * WW + w6] + qbv) + dwv[w6] * dinv;
        mx = fmaxf(mx, sc[w6]);
      }
      float ssum = 0.f;
      #pragma unroll
      for (int w6 = 0; w6 < WW; ++w6) { sc[w6] = expf(sc[w6] - mx); ssum += sc[w6]; }
      float sinv = 1.f / ssum;
      #pragma unroll
      for (int w6 = 0; w6 < WW; ++w6) attn[r][w6] = sc[w6] * sinv;
    }
  }

  // ---- P5: Aagg = attn-weighted evo combine (chunked), pooled = Aagg @ Wv_h + bv ----
  {
    f32x4 pacc[4] = {};
    unsigned short* my = scr_s + wv * (BM * SCS);
    #pragma unroll
    for (int c = 0; c < 4; ++c) {
      #pragma unroll
      for (int r = 0; r < 4; ++r) {
        int e = lq * 4 + r;
        float a0 = 0, a1 = 0, a2 = 0, a3 = 0, a4 = 0, a5 = 0, a6 = 0, a7 = 0;
        #pragma unroll
        for (int w6 = 0; w6 < WW; ++w6) {
          int row = e * WW + w6;
          const uint4 vv = *(const uint4*)&evo_s[row * EVS + evsw(row, c * 128 + l16 * 8)];
          float aw = attn[r][w6];
          a0 += aw * bflo(vv.x); a1 += aw * bfhi(vv.x);
          a2 += aw * bflo(vv.y); a3 += aw * bfhi(vv.y);
          a4 += aw * bflo(vv.z); a5 += aw * bfhi(vv.z);
          a6 += aw * bflo(vv.w); a7 += aw * bfhi(vv.w);
        }
        uint4 o;
        o.x = (unsigned)f2bf(a0) | ((unsigned)f2bf(a1) << 16);
        o.y = (unsigned)f2bf(a2) | ((unsigned)f2bf(a3) << 16);
        o.z = (unsigned)f2bf(a4) | ((unsigned)f2bf(a5) << 16);
        o.w = (unsigned)f2bf(a6) | ((unsigned)f2bf(a7) << 16);
        *(uint4*)&my[e * SCS + l16 * 8] = o;
      }
      __syncthreads();
      #pragma unroll
      for (int kst = 0; kst < 4; ++kst) {
        bf16x8 a = *(const bf16x8*)&my[l16 * SCS + kst * 32 + lq * 8];
        #pragma unroll
        for (int ct = 0; ct < 4; ++ct) {
          bf16x8 b = *(const bf16x8*)&wvT[(wv * 64 + ct * 16 + l16) * DD + c * 128 + kst * 32 + lq * 8];
          pacc[ct] = __builtin_amdgcn_mfma_f32_16x16x32_bf16(a, b, pacc[ct], 0, 0, 0);
        }
      }
      __syncthreads();
    }
    #pragma unroll
    for (int ct = 0; ct < 4; ++ct) {
      int col = wv * 64 + ct * 16 + l16;
      float bvv = bv[col];
      #pragma unroll
      for (int r = 0; r < 4; ++r)
        q_s[(lq * 4 + r) * QS + col] = f2bf(pacc[ct][r] + bvv);   // pooled overwrites Q
    }
  }
  __syncthreads();

  // ---- P6: hmid = gelu(pooled @ W1 + b1); logit partials ----
  {
    f32x4 hacc[2] = {};
    #pragma unroll
    for (int kst = 0; kst < 16; ++kst) {
      bf16x8 a = *(const bf16x8*)&q_s[l16 * QS + kst * 32 + lq * 8];
      #pragma unroll
      for (int ct = 0; ct < 2; ++ct) {
        bf16x8 b = *(const bf16x8*)&w1T[(wv * 32 + ct * 16 + l16) * DD + kst * 32 + lq * 8];
        hacc[ct] = __builtin_amdgcn_mfma_f32_16x16x32_bf16(a, b, hacc[ct], 0, 0, 0);
      }
    }
    float lg[4] = {0.f, 0.f, 0.f, 0.f};
    #pragma unroll
    for (int ct = 0; ct < 2; ++ct) {
      int m = wv * 32 + ct * 16 + l16;
      float b1v = b1[m], w2v = W2[m];
      #pragma unroll
      for (int r = 0; r < 4; ++r) {
        float x = hacc[ct][r] + b1v;
        float g = 0.5f * x * (1.f + erff(x * 0.70710678118f));
        lg[r] += g * w2v;
      }
    }
    #pragma unroll
    for (int r = 0; r < 4; ++r) {
      #pragma unroll
      for (int m = 1; m <= 8; m <<= 1) lg[r] += __shfl_xor(lg[r], m);
    }
    if (l16 == 0) {
      #pragma unroll
      for (int r = 0; r < 4; ++r) logit_s[(lq * 4 + r) * NH + wv] = lg[r];
    }
  }
  __syncthreads();

  // ---- P7: combine + sigmoid ----
  if (t < BM) {
    float s = 0.f;
    #pragma unroll
    for (int w8 = 0; w8 < NH; ++w8) s += logit_s[t * NH + w8];
    s += b2[0] + conf_s[t];
    out[e0 + t] = 1.f / (1.f + expf(-s));
  }
}

extern "C" void kernel_launch(void* const* d_in, const int* in_sizes, int n_in,
                              void* d_out, int out_size, void* d_ws, size_t ws_size,
                              hipStream_t stream) {
  (void)in_sizes; (void)n_in; (void)out_size; (void)ws_size;
  const float* h_i = (const float*)d_in[0];
  const float* evo = (const float*)d_in[1];
  const float* vi  = (const float*)d_in[2];
  const float* vj  = (const float*)d_in[3];
  const float* Wq  = (const float*)d_in[4];
  const float* bq  = (const float*)d_in[5];
  const float* Wk  = (const float*)d_in[6];
  const float* bk  = (const float*)d_in[7];
  const float* Wv  = (const float*)d_in[8];
  const float* bv  = (const float*)d_in[9];
  const float* ld  = (const float*)d_in[10];
  const float* W1  = (const float*)d_in[11];
  const float* b1  = (const float*)d_in[12];
  const float* W2  = (const float*)d_in[13];
  const float* b2  = (const float*)d_in[14];
  float* out = (float*)d_out;

  unsigned short* ws  = (unsigned short*)d_ws;
  unsigned short* wqT = ws;            // [512][512] bf16, WqT[n][k]=Wq[k][n]
  unsigned short* wkB = ws + 262144;   // [512][512] bf16, plain Wk
  unsigned short* wvT = ws + 524288;   // [512][512] bf16, WvT[n][k]=Wv[k][n]
  unsigned short* w1T = ws + 786432;   // [256][512] bf16, W1T[m][k]=W1[k][m]

  k_tr_bf16<<<64, 256, 0, stream>>>(Wq, wqT, 512, 512);
  k_cvt4<<<256, 256, 0, stream>>>(Wk, wkB, 65536);
  k_tr_bf16<<<64, 256, 0, stream>>>(Wv, wvT, 512, 512);
  k_tr_bf16<<<32, 256, 0, stream>>>(W1, w1T, 512, 256);
  trust_main<<<3125, 512, 0, stream>>>(h_i, evo, vi, vj, bq, bk, bv, ld, b1, W2, b2,
                                       wqT, wkB, wvT, w1T, out);
}